// Round 5
// baseline (288.562 us; speedup 1.0000x reference)
//
#include <hip/hip_runtime.h>

// DfOpCoefLoop: deep-filtering over first 96 freq bins, 5-tap complex FIR in
// time (lookahead 2), alpha-blended with dry spec; remaining bins copied.
//
// spec  : (B=32, 1, T=1000, F=481, 2) f32   = 123.1 MB   (row = 962 f32 = 3848 B)
// coefs : (B=32, T=1000, ORDER=5, DF=96, 2) = 122.9 MB   (row = 960 f32 = 3840 B, 16B-aligned)
// alpha : (B=32, T=1000, 1) f32
// out   : same shape as spec                = 123.1 MB
//
// Memory-bound: ~369 MB mandatory traffic -> ~58 us floor @6.3 TB/s.
// R4 measured 77 us @ 8B/lane; this round: 16B/lane on coefs + tail copy.

typedef float f2 __attribute__((ext_vector_type(2)));
typedef float f4 __attribute__((ext_vector_type(4)));

#define ORDER 5
#define TPAD  2        // ORDER - LOOKAHEAD - 1
#define NDF   96
#define NF    481
#define TT    1000
#define BB    32
#define NROWS (BB * TT)
#define ROWF  (NF * 2)           // 962 floats per spec/out row
#define CROWF (ORDER * NDF * 2)  // 960 floats per coef row

__global__ __launch_bounds__(256) void df_kernel(
    const float* __restrict__ spec,
    const float* __restrict__ coefs,
    const float* __restrict__ alpha,
    float* __restrict__ out)
{
    // XCD-chunked swizzle (bijective, NROWS%8==0): rows r-2..r+2 are processed
    // on the same XCD at nearly the same time -> tap reuse is an own-L2 hit.
    const int bid = blockIdx.x;
    const int row = (bid & 7) * (NROWS / 8) + (bid >> 3);
    const int t   = row % TT;              // block-uniform
    const int tid = threadIdx.x;

    const float* __restrict__ srow = spec + (size_t)row * ROWF;
    float* __restrict__       orow = out  + (size_t)row * ROWF;

    if (tid < 48) {
        // ---- DF bins (2*tid, 2*tid+1): 5-tap complex FIR + alpha blend ----
        const float* __restrict__ crow = coefs + (size_t)row * CROWF;
        const float a   = alpha[row];      // uniform scalar
        const float oma = 1.0f - a;

        float re0 = 0.f, im0 = 0.f, re1 = 0.f, im1 = 0.f;
        f2 s0, s1;                         // dry (center-tap) values
#pragma unroll
        for (int i = 0; i < ORDER; ++i) {
            const int ts = t + i - TPAD;   // block-uniform validity
            if (ts >= 0 && ts < TT) {
                const float* w = spec + (size_t)(row + i - TPAD) * ROWF + 4 * tid;
                const f2 w0 = *(const f2*)(w);       // 8B-aligned always
                const f2 w1 = *(const f2*)(w + 2);
                // coef row 3840B-aligned, tap offset i*768B, lane offset 16B -> f4 ok
                const f4 c = __builtin_nontemporal_load(
                    (const f4*)(crow + i * (NDF * 2) + 4 * tid));
                re0 += w0.x * c.x - w0.y * c.y;
                im0 += w0.y * c.x + w0.x * c.y;
                re1 += w1.x * c.z - w1.y * c.w;
                im1 += w1.y * c.z + w1.x * c.w;
                if (i == TPAD) { s0 = w0; s1 = w1; }   // center tap always valid
            }
        }
        f2 o0, o1;
        o0.x = re0 * a + s0.x * oma;  o0.y = im0 * a + s0.y * oma;
        o1.x = re1 * a + s1.x * oma;  o1.y = im1 * a + s1.y * oma;
        __builtin_nontemporal_store(o0, (f2*)(orow + 4 * tid));
        __builtin_nontemporal_store(o1, (f2*)(orow + 4 * tid + 2));
    } else {
        // ---- tail bins [96,481): 770 floats, copied with aligned float4 ----
        // Row byte-base alternates 0/8 mod 16: even rows aligned at float 192,
        // odd rows aligned at float 194.
        if ((row & 1) == 0) {
            if (tid < 240) {               // 192 aligned f4: floats [192,960)
                const int k = tid - 48;
                const f4 v = __builtin_nontemporal_load((const f4*)(srow + 192 + 4 * k));
                __builtin_nontemporal_store(v, (f4*)(orow + 192 + 4 * k));
            } else if (tid == 240) {       // trailing f2: floats 960,961
                const f2 v = __builtin_nontemporal_load((const f2*)(srow + 960));
                __builtin_nontemporal_store(v, (f2*)(orow + 960));
            }
        } else {
            if (tid == 48) {               // leading f2: floats 192,193
                const f2 v = __builtin_nontemporal_load((const f2*)(srow + 192));
                __builtin_nontemporal_store(v, (f2*)(orow + 192));
            } else if (tid < 241) {        // 192 aligned f4: floats [194,962)
                const int k = tid - 49;
                const f4 v = __builtin_nontemporal_load((const f4*)(srow + 194 + 4 * k));
                __builtin_nontemporal_store(v, (f4*)(orow + 194 + 4 * k));
            }
        }
    }
}

extern "C" void kernel_launch(void* const* d_in, const int* in_sizes, int n_in,
                              void* d_out, int out_size, void* d_ws, size_t ws_size,
                              hipStream_t stream) {
    const float* spec  = (const float*)d_in[0];
    const float* coefs = (const float*)d_in[1];
    const float* alpha = (const float*)d_in[2];
    float* out = (float*)d_out;

    dim3 grid(NROWS);   // one block per (b,t) row
    dim3 block(256);
    df_kernel<<<grid, block, 0, stream>>>(spec, coefs, alpha, out);
}